// Round 17
// baseline (175.082 us; speedup 1.0000x reference)
//
#include <hip/hip_runtime.h>
#include <hip/hip_bf16.h>

// ActorNetwork fused pipeline for MI355X — round 17.
// Base = r16. Single change: bel/x1 LDS tiles single-plane bf16; grumlp phases
// 3/5 use 2 MFMA per weight hi/lo pair. All weights remain hi/lo split.

typedef unsigned short u16;
typedef unsigned int   u32;
typedef __attribute__((ext_vector_type(8))) short bf16x8;
typedef __attribute__((ext_vector_type(4))) float f32x4;

#define KFUSE  672   // 641 padded to 21*32
#define ACT_TOT (8192*16)

__device__ __forceinline__ u16 f2bf(float x){
  u32 u = __float_as_uint(x);
  u += 0x7fffu + ((u >> 16) & 1u);   // round-to-nearest-even
  return (u16)(u >> 16);
}
__device__ __forceinline__ float bf2f(u16 h){ return __uint_as_float(((u32)h) << 16); }

// one MFMA B-fragment (64 lanes) from fp32 src
__device__ __forceinline__ void frag_one(const float* __restrict__ src, int ld, int col0,
                                         int NT, u16* __restrict__ dhi, u16* __restrict__ dlo,
                                         int f, int fsrc, int l){
  int kt = fsrc / NT, nt = fsrc % NT;
  int kbase = kt*32 + (l >> 4)*8, n = col0 + nt*16 + (l & 15);
  size_t o = ((size_t)f*64 + l)*8;
  #pragma unroll
  for(int i = 0; i < 8; ++i){
    float w = src[(size_t)(kbase + i)*ld + n];
    u16 h = f2bf(w);
    dhi[o + i] = h;
    dlo[o + i] = f2bf(w - bf2f(h));
  }
}

// Wbig fragment computed inline: row r<129 -> fusion_W; 129..640 -> Wg x fW; pad 0
__device__ __forceinline__ void frag_wbig(const float* __restrict__ fW,
                                          const float* __restrict__ Wg,
                                          u16* __restrict__ dhi, u16* __restrict__ dlo,
                                          int f, int l){
  int kt = f / 16, nt = f % 16;
  int kbase = kt*32 + (l >> 4)*8, n = nt*16 + (l & 15);
  size_t o = ((size_t)f*64 + l)*8;
  #pragma unroll
  for(int i = 0; i < 8; ++i){
    int r = kbase + i;
    float v;
    if(r < 129) v = fW[(size_t)r*256 + n];
    else if(r < 641){
      int h = (r - 129) >> 7, kk = (r - 129) & 127;
      float s = 0.f;
      for(int ff = 0; ff < 64; ++ff)
        s += Wg[kk*256 + h*64 + ff] * fW[(size_t)(129 + h*64 + ff)*256 + n];
      v = s;
    } else v = 0.f;
    u16 hh = f2bf(v);
    dhi[o + i] = hh;
    dlo[o + i] = f2bf(v - bf2f(hh));
  }
}

// ---------- single prep kernel: probe+wa + all weight frags ----------
#define P_FF0   1
#define P_WRZ0  85
#define P_WIN0  213
#define P_WHN0  245
#define P_F10   277
#define P_F20   309
// grid = 325
__global__ __launch_bounds__(256) void k_prep(
    const unsigned char* __restrict__ maskb, int* __restrict__ flag,
    const float* __restrict__ Wg, const float* __restrict__ ag,
    float* __restrict__ was, float* __restrict__ wad,
    const float* __restrict__ fW,
    const float* __restrict__ Wih, const float* __restrict__ Whh,
    const float* __restrict__ W1, const float* __restrict__ W2,
    u16* __restrict__ ffh, u16* __restrict__ ffl,
    u16* __restrict__ wrzh, u16* __restrict__ wrzl,
    u16* __restrict__ winh, u16* __restrict__ winl,
    u16* __restrict__ whnh, u16* __restrict__ whnl,
    u16* __restrict__ f1h, u16* __restrict__ f1l,
    u16* __restrict__ f2h, u16* __restrict__ f2l)
{
  int bx = blockIdx.x, t = threadIdx.x;
  if(bx == 0){
    if(t == 0){
      int s = 0;
      for(int i = 1; i < 256; i += 4) s += maskb[i];
      *flag = (s == 0) ? 1 : 0;
    }
    #pragma unroll
    for(int v = 0; v < 2; ++v){
      int idx = v*256 + t, k = idx & 127, h = idx >> 7;
      float s = 0.f, d = 0.f;
      for(int f = 0; f < 64; ++f){
        float w = Wg[k*256 + h*64 + f];
        s += w * ag[h*128 + f];
        d += w * ag[h*128 + 64 + f];
      }
      was[k*4 + h] = s; wad[k*4 + h] = d;
    }
  } else if(bx < P_WRZ0){
    int sub = t >> 6, l = t & 63;
    int f = (bx - P_FF0)*4 + sub;          // 0..335
    frag_wbig(fW, Wg, ffh, ffl, f, l);
  } else {
    int sub = t >> 6, l = t & 63;
    if(bx < P_WIN0){        // rz: 512 frags (Wih 0..255, Whh 256..511)
      int idx = (bx - P_WRZ0)*4 + sub;
      if(idx < 256) frag_one(Wih, 768, 0, 32, wrzh, wrzl, idx, idx, l);
      else          frag_one(Whh, 768, 0, 32, wrzh, wrzl, idx, idx - 256, l);
    } else if(bx < P_WHN0){ // Wih n
      int f = (bx - P_WIN0)*4 + sub;
      frag_one(Wih, 768, 512, 16, winh, winl, f, f, l);
    } else if(bx < P_F10){  // Whh n
      int f = (bx - P_WHN0)*4 + sub;
      frag_one(Whh, 768, 512, 16, whnh, whnl, f, f, l);
    } else if(bx < P_F20){  // W1
      int f = (bx - P_F10)*4 + sub;
      frag_one(W1, 256, 0, 16, f1h, f1l, f, f, l);
    } else {                // W2
      int f = (bx - P_F20)*4 + sub;
      frag_one(W2, 128, 0, 8, f2h, f2l, f, f, l);
    }
  }
}

// ---------- GAT kernel: main 8192 + h-split tail 1024; single-plane outputs ----------
__global__ __launch_bounds__(256) void k_gat(
    const float* __restrict__ nbg, const float* __restrict__ node,
    const void* __restrict__ maskp, const int* __restrict__ flagp,
    const float* __restrict__ was, const float* __restrict__ wad,
    u16* __restrict__ xhi,
    const float* __restrict__ hidden,
    u16* __restrict__ acath)
{
  int t = threadIdx.x;
  if(blockIdx.x >= 8192){
    int i = (blockIdx.x - 8192)*256 + t;
    int idx8 = i*8, row = idx8 >> 8, col = idx8 & 255;
    const float4* p = (const float4*)(hidden + (size_t)idx8);
    float4 v0 = p[0], v1 = p[1];
    float vv[8] = {v0.x,v0.y,v0.z,v0.w,v1.x,v1.y,v1.z,v1.w};
    u16 h8[8];
    #pragma unroll
    for(int q = 0; q < 8; ++q) h8[q] = f2bf(vv[q]);
    uint4 uh = { (u32)h8[0] | ((u32)h8[1]<<16), (u32)h8[2] | ((u32)h8[3]<<16),
                 (u32)h8[4] | ((u32)h8[5]<<16), (u32)h8[6] | ((u32)h8[7]<<16) };
    size_t off = (size_t)row*512 + 256 + col;
    *(uint4*)(acath + off) = uh;
    return;
  }

  __shared__ float s_nb[8192];
  __shared__ float s_ep[1024];
  __shared__ float s_alpha[256];
  int b = blockIdx.x;
  const float* nb = nbg + (size_t)b*8192;
  const int isint = *flagp;

  #pragma unroll
  for(int q = 0; q < 8; ++q){
    int f = q*256 + t;
    int n = f >> 5, ch = f & 31;
    float4 v = *(const float4*)(nb + f*4);
    *(float4*)(s_nb + (n*32 + (ch ^ (n & 31)))*4) = v;
  }

  if(t < 129){
    float v;
    if(t < 2){
      float ph = node[(size_t)b*128] * (6.2831853071795864769f / 24.0f);
      v = (t == 0) ? sinf(ph) : cosf(ph);
    } else v = node[(size_t)b*128 + (t-1)];
    xhi[(size_t)b*KFUSE + t] = f2bf(v);
  } else if(t < 160){
    xhi[(size_t)b*KFUSE + 641 + (t - 129)] = 0;
  }
  __syncthreads();

  {
    int n = t & 63, c = t >> 6;
    int cu = __builtin_amdgcn_readfirstlane(c);
    const float* wadc = wad + cu*128;
    float adx = 0.f, ady = 0.f, adz = 0.f, adw = 0.f;
    #pragma unroll
    for(int q = 0; q < 8; ++q){
      int ch = c*8 + q;
      float4 v = *(const float4*)(s_nb + (n*32 + (ch ^ (n & 31)))*4);
      float vv[4] = {v.x, v.y, v.z, v.w};
      #pragma unroll
      for(int i2 = 0; i2 < 4; ++i2){
        float4 wd = *(const float4*)(wadc + (q*4 + i2)*4);
        adx += vv[i2]*wd.x; ady += vv[i2]*wd.y; adz += vv[i2]*wd.z; adw += vv[i2]*wd.w;
      }
    }
    float4 ad = {adx, ady, adz, adw};
    *(float4*)(s_ep + (c*64 + n)*4) = ad;
  }
  __syncthreads();

  {
    int n2 = t & 63, h2 = t >> 6;
    float es = 0.f;
    #pragma unroll
    for(int ii = 0; ii < 2; ++ii){
      int k = n2*2 + ii;
      float v0 = s_nb[(k >> 2)*4 + (k & 3)];
      es += v0 * was[k*4 + h2];
    }
    for(int off = 32; off; off >>= 1) es += __shfl_xor(es, off);
    float ed = s_ep[n2*4 + h2] + s_ep[(64+n2)*4 + h2]
             + s_ep[(128+n2)*4 + h2] + s_ep[(192+n2)*4 + h2];
    float e = es + ed;
    e = (e > 0.f) ? e : 0.2f*e;
    bool valid;
    if(isint) valid = ((const u32*)maskp)[(size_t)b*64 + n2] != 0u;
    else      valid = ((const unsigned char*)maskp)[(size_t)b*64 + n2] != 0;
    float ev = valid ? e : -1e30f;
    float m = ev;
    for(int off = 32; off; off >>= 1) m = fmaxf(m, __shfl_xor(m, off));
    float p = valid ? expf(ev - m) : 0.f;
    float s = p;
    for(int off = 32; off; off >>= 1) s += __shfl_xor(s, off);
    s_alpha[n2*4 + h2] = p / s;   // [n][4h]
  }
  __syncthreads();

  {
    int c2 = t & 31, hp = (t >> 6) & 1, half = t >> 7;
    int sub = (t >> 5) & 1;
    float4 a0 = {0.f,0.f,0.f,0.f}, a1 = {0.f,0.f,0.f,0.f};
    int nbase = half*32 + sub*16;
    #pragma unroll
    for(int i = 0; i < 16; ++i){
      int n = nbase + i;
      float4 v = *(const float4*)(s_nb + (n*32 + (c2 ^ (n & 31)))*4);
      float2 ap = *(const float2*)(s_alpha + n*4 + hp*2);
      a0.x += ap.x*v.x; a0.y += ap.x*v.y; a0.z += ap.x*v.z; a0.w += ap.x*v.w;
      a1.x += ap.y*v.x; a1.y += ap.y*v.y; a1.z += ap.y*v.z; a1.w += ap.y*v.w;
    }
    a0.x += __shfl_xor(a0.x, 32); a0.y += __shfl_xor(a0.y, 32);
    a0.z += __shfl_xor(a0.z, 32); a0.w += __shfl_xor(a0.w, 32);
    a1.x += __shfl_xor(a1.x, 32); a1.y += __shfl_xor(a1.y, 32);
    a1.z += __shfl_xor(a1.z, 32); a1.w += __shfl_xor(a1.w, 32);
    __syncthreads();
    if((t & 63) < 32){
      int w = t >> 6;
      *(float4*)(s_ep + (w*32 + c2)*8 + 0) = a0;
      *(float4*)(s_ep + (w*32 + c2)*8 + 4) = a1;
    }
  }
  __syncthreads();
  if(t < 128){
    int h = t >> 5, cc = t & 31;
    int hp2 = h >> 1, slot = h & 1;
    float4 p0 = *(const float4*)(s_ep + ((0*2 + hp2)*32 + cc)*8 + slot*4);
    float4 p1 = *(const float4*)(s_ep + ((1*2 + hp2)*32 + cc)*8 + slot*4);
    float vv[4] = {p0.x+p1.x, p0.y+p1.y, p0.z+p1.z, p0.w+p1.w};
    size_t o = (size_t)b*KFUSE + 129 + h*128 + cc*4;
    #pragma unroll
    for(int i = 0; i < 4; ++i) xhi[o+i] = f2bf(vv[i]);
  }
}

// ---------- fusion GEMM: A single-plane, B hi/lo split; single-plane output ----------
template<int KT, int NT_TOT, int NPW, int ROWF>
__global__ __launch_bounds__(256) void k_gemmF(
    const u16* __restrict__ xhi, int lda,
    const u16* __restrict__ wfhi, const u16* __restrict__ wflo,
    const float* __restrict__ bias,
    u16* __restrict__ ohi, int ost, int ocol)
{
  int l = threadIdx.x & 63, w = threadIdx.x >> 6;
  int m0 = blockIdx.x * (16*ROWF);
  int ntbase = blockIdx.y * (4*NPW) + w*NPW;
  f32x4 acc[NPW][ROWF];
  #pragma unroll
  for(int j = 0; j < NPW; ++j)
    #pragma unroll
    for(int rf = 0; rf < ROWF; ++rf) acc[j][rf] = (f32x4){0.f,0.f,0.f,0.f};
  size_t arow[ROWF];
  #pragma unroll
  for(int rf = 0; rf < ROWF; ++rf)
    arow[rf] = (size_t)(m0 + rf*16 + (l & 15))*lda + (size_t)((l >> 4)*8);
  bf16x8 ah[ROWF], bhc[NPW], blc[NPW];
  #pragma unroll
  for(int rf = 0; rf < ROWF; ++rf)
    ah[rf] = *(const bf16x8*)(xhi + arow[rf]);
  #pragma unroll
  for(int j = 0; j < NPW; ++j){
    size_t bo = ((size_t)(ntbase + j)*64 + l)*8;
    bhc[j] = *(const bf16x8*)(wfhi + bo);
    blc[j] = *(const bf16x8*)(wflo + bo);
  }
  for(int kt = 0; kt < KT; ++kt){
    bf16x8 ahn[ROWF], bhn[NPW], bln[NPW];
    if(kt + 1 < KT){
      #pragma unroll
      for(int rf = 0; rf < ROWF; ++rf)
        ahn[rf] = *(const bf16x8*)(xhi + arow[rf] + (kt+1)*32);
      #pragma unroll
      for(int j = 0; j < NPW; ++j){
        size_t bo = ((size_t)((kt+1)*NT_TOT + ntbase + j)*64 + l)*8;
        bhn[j] = *(const bf16x8*)(wfhi + bo);
        bln[j] = *(const bf16x8*)(wflo + bo);
      }
    }
    #pragma unroll
    for(int j = 0; j < NPW; ++j){
      #pragma unroll
      for(int rf = 0; rf < ROWF; ++rf){
        acc[j][rf] = __builtin_amdgcn_mfma_f32_16x16x32_bf16(ah[rf], bhc[j], acc[j][rf], 0, 0, 0);
        acc[j][rf] = __builtin_amdgcn_mfma_f32_16x16x32_bf16(ah[rf], blc[j], acc[j][rf], 0, 0, 0);
      }
    }
    #pragma unroll
    for(int rf = 0; rf < ROWF; ++rf) ah[rf] = ahn[rf];
    #pragma unroll
    for(int j = 0; j < NPW; ++j){ bhc[j] = bhn[j]; blc[j] = bln[j]; }
  }
  #pragma unroll
  for(int j = 0; j < NPW; ++j){
    int col = (ntbase + j)*16 + (l & 15);
    float bv = bias[col];
    #pragma unroll
    for(int rf = 0; rf < ROWF; ++rf){
      int r0 = m0 + rf*16 + (l >> 4)*4;
      #pragma unroll
      for(int q = 0; q < 4; ++q){
        float y = fmaxf(acc[j][rf][q] + bv, 0.f);
        ohi[(size_t)(r0 + q)*ost + ocol + col] = f2bf(y);
      }
    }
  }
}

// ---------- mega kernel: all activations single-plane; weights split ----------
#define BSTR 264   // padded u16 stride for bel/x1 tile
#define XSTR 132   // padded f32 stride for x2 tile
__global__ __launch_bounds__(512) void k_grumlp(
    const u16* __restrict__ ah_,
    const u16* __restrict__ wrzh, const u16* __restrict__ wrzl,
    const u16* __restrict__ winh, const u16* __restrict__ winl,
    const u16* __restrict__ whnh, const u16* __restrict__ whnl,
    const u16* __restrict__ f1h, const u16* __restrict__ f1l,
    const u16* __restrict__ f2h, const u16* __restrict__ f2l,
    const float* __restrict__ bih, const float* __restrict__ bhh,
    const float* __restrict__ hidden, const float* __restrict__ lng,
    const float* __restrict__ lnb,
    const float* __restrict__ b1, const float* __restrict__ b2,
    const float* __restrict__ W3, const float* __restrict__ b3,
    float* __restrict__ hout, float* __restrict__ act)
{
  __shared__ float s_s1[256], s_s2[256], s_mu[32], s_rs[32];
  __shared__ u16 s_bh[32*BSTR];       // bel tile, later x1 tile (single-plane)
  __shared__ float s_x2[32*XSTR];
  __shared__ float sW3[2048];
  int t = threadIdx.x;
  int l = t & 63, w = t >> 6;   // 8 waves
  int m0 = blockIdx.x*32;
  for(int i = t; i < 2048; i += 512) sW3[i] = W3[i];

  // ---- phase 1: GRU gates via MFMA (A single-plane, weights split) ----
  f32x4 ar[2][2], az[2][2], aa[2][2], ab[2][2];
  #pragma unroll
  for(int j = 0; j < 2; ++j)
    #pragma unroll
    for(int rf = 0; rf < 2; ++rf){
      ar[j][rf] = (f32x4){0.f,0.f,0.f,0.f}; az[j][rf] = (f32x4){0.f,0.f,0.f,0.f};
      aa[j][rf] = (f32x4){0.f,0.f,0.f,0.f}; ab[j][rf] = (f32x4){0.f,0.f,0.f,0.f};
    }
  size_t arow[2];
  #pragma unroll
  for(int rf = 0; rf < 2; ++rf)
    arow[rf] = (size_t)(m0 + rf*16 + (l & 15))*512 + (size_t)((l >> 4)*8);
  for(int kt = 0; kt < 16; ++kt){
    bf16x8 xh[2];
    #pragma unroll
    for(int rf = 0; rf < 2; ++rf)
      xh[rf] = *(const bf16x8*)(ah_ + arow[rf] + kt*32);
    #pragma unroll
    for(int j = 0; j < 2; ++j){
      int nt = w*2 + j;
      size_t bo = ((size_t)(kt*32 + nt)*64 + l)*8;
      bf16x8 bh = *(const bf16x8*)(wrzh + bo);
      bf16x8 bl = *(const bf16x8*)(wrzl + bo);
      size_t bo2 = bo + (size_t)16*64*8;
      bf16x8 bh2 = *(const bf16x8*)(wrzh + bo2);
      bf16x8 bl2 = *(const bf16x8*)(wrzl + bo2);
      #pragma unroll
      for(int rf = 0; rf < 2; ++rf){
        ar[j][rf] = __builtin_amdgcn_mfma_f32_16x16x32_bf16(xh[rf], bh, ar[j][rf], 0, 0, 0);
        ar[j][rf] = __builtin_amdgcn_mfma_f32_16x16x32_bf16(xh[rf], bl, ar[j][rf], 0, 0, 0);
        az[j][rf] = __builtin_amdgcn_mfma_f32_16x16x32_bf16(xh[rf], bh2, az[j][rf], 0, 0, 0);
        az[j][rf] = __builtin_amdgcn_mfma_f32_16x16x32_bf16(xh[rf], bl2, az[j][rf], 0, 0, 0);
      }
    }
  }
  for(int kt = 0; kt < 8; ++kt){
    bf16x8 fh[2], gh[2];
    #pragma unroll
    for(int rf = 0; rf < 2; ++rf){
      fh[rf] = *(const bf16x8*)(ah_ + arow[rf] + kt*32);
      gh[rf] = *(const bf16x8*)(ah_ + arow[rf] + 256 + kt*32);
    }
    #pragma unroll
    for(int j = 0; j < 2; ++j){
      int nt = w*2 + j;
      size_t bo = ((size_t)(kt*16 + nt)*64 + l)*8;
      bf16x8 bh = *(const bf16x8*)(winh + bo);
      bf16x8 bl = *(const bf16x8*)(winl + bo);
      bf16x8 ch = *(const bf16x8*)(whnh + bo);
      bf16x8 cl2 = *(const bf16x8*)(whnl + bo);
      #pragma unroll
      for(int rf = 0; rf < 2; ++rf){
        aa[j][rf] = __builtin_amdgcn_mfma_f32_16x16x32_bf16(fh[rf], bh, aa[j][rf], 0, 0, 0);
        aa[j][rf] = __builtin_amdgcn_mfma_f32_16x16x32_bf16(fh[rf], bl, aa[j][rf], 0, 0, 0);
        ab[j][rf] = __builtin_amdgcn_mfma_f32_16x16x32_bf16(gh[rf], ch, ab[j][rf], 0, 0, 0);
        ab[j][rf] = __builtin_amdgcn_mfma_f32_16x16x32_bf16(gh[rf], cl2, ab[j][rf], 0, 0, 0);
      }
    }
  }
  int cl = l & 15, rq = l >> 4;
  float hnew[2][2][4];
  float s1p[2][4], s2p[2][4];
  #pragma unroll
  for(int rf = 0; rf < 2; ++rf)
    #pragma unroll
    for(int q = 0; q < 4; ++q){ s1p[rf][q] = 0.f; s2p[rf][q] = 0.f; }
  #pragma unroll
  for(int j = 0; j < 2; ++j){
    int col = w*32 + j*16 + cl;
    float br = bih[col] + bhh[col];
    float bz = bih[256+col] + bhh[256+col];
    float bi = bih[512+col];
    float bh2 = bhh[512+col];
    #pragma unroll
    for(int rf = 0; rf < 2; ++rf){
      #pragma unroll
      for(int q = 0; q < 4; ++q){
        int row = m0 + rf*16 + rq*4 + q;
        float rs = ar[j][rf][q] + br;
        float zs = az[j][rf][q] + bz;
        float in_ = aa[j][rf][q] + bi;
        float hn  = ab[j][rf][q] + bh2;
        float h   = hidden[(size_t)row*256 + col];
        float r = 1.f/(1.f + expf(-rs));
        float z = 1.f/(1.f + expf(-zs));
        float nv = tanhf(in_ + r*hn);
        float hv = (1.f - z)*nv + z*h;
        hnew[j][rf][q] = hv;
        hout[(size_t)row*256 + col] = hv;
        s1p[rf][q] += hv; s2p[rf][q] += hv*hv;
      }
    }
  }
  #pragma unroll
  for(int rf = 0; rf < 2; ++rf)
    #pragma unroll
    for(int q = 0; q < 4; ++q){
      float a = s1p[rf][q], b2v = s2p[rf][q];
      for(int off = 1; off < 16; off <<= 1){
        a += __shfl_xor(a, off); b2v += __shfl_xor(b2v, off);
      }
      if(cl == 0){
        int rloc = rf*16 + rq*4 + q;
        s_s1[w*32 + rloc] = a; s_s2[w*32 + rloc] = b2v;
      }
    }
  __syncthreads();
  if(t < 32){
    int rloc = t;
    float t1 = 0.f, t2 = 0.f;
    #pragma unroll
    for(int ww = 0; ww < 8; ++ww){ t1 += s_s1[ww*32 + rloc]; t2 += s_s2[ww*32 + rloc]; }
    float mu = t1 * (1.f/256.f);
    float var = t2 * (1.f/256.f) - mu*mu;
    s_mu[rloc] = mu; s_rs[rloc] = rsqrtf(var + 1e-5f);
  }
  __syncthreads();
  // ---- phase 2: bel -> LDS tile (single-plane) ----
  #pragma unroll
  for(int j = 0; j < 2; ++j){
    int col = w*32 + j*16 + cl;
    float g = lng[col], bb = lnb[col];
    #pragma unroll
    for(int rf = 0; rf < 2; ++rf){
      #pragma unroll
      for(int q = 0; q < 4; ++q){
        int rloc = rf*16 + rq*4 + q;
        float bel = (hnew[j][rf][q] - s_mu[rloc]) * s_rs[rloc] * g + bb;
        s_bh[rloc*BSTR + col] = f2bf(bel);
      }
    }
  }
  __syncthreads();
  // ---- phase 3: x1 = relu(bel @ W1 + b1), bel single-plane from LDS ----
  f32x4 ax1[2][2];
  #pragma unroll
  for(int j = 0; j < 2; ++j)
    #pragma unroll
    for(int rf = 0; rf < 2; ++rf) ax1[j][rf] = (f32x4){0.f,0.f,0.f,0.f};
  for(int kt = 0; kt < 8; ++kt){
    bf16x8 xh[2];
    #pragma unroll
    for(int rf = 0; rf < 2; ++rf){
      int off = (rf*16 + (l & 15))*BSTR + kt*32 + (l >> 4)*8;
      xh[rf] = *(const bf16x8*)(s_bh + off);
    }
    #pragma unroll
    for(int j = 0; j < 2; ++j){
      size_t bo = ((size_t)(kt*16 + w*2 + j)*64 + l)*8;
      bf16x8 bh = *(const bf16x8*)(f1h + bo);
      bf16x8 bl = *(const bf16x8*)(f1l + bo);
      #pragma unroll
      for(int rf = 0; rf < 2; ++rf){
        ax1[j][rf] = __builtin_amdgcn_mfma_f32_16x16x32_bf16(xh[rf], bh, ax1[j][rf], 0, 0, 0);
        ax1[j][rf] = __builtin_amdgcn_mfma_f32_16x16x32_bf16(xh[rf], bl, ax1[j][rf], 0, 0, 0);
      }
    }
  }
  __syncthreads();
  // ---- phase 4: x1 -> LDS tile (single-plane, overwrite bel) ----
  #pragma unroll
  for(int j = 0; j < 2; ++j){
    int col = (w*2 + j)*16 + cl;
    float bv = b1[col];
    #pragma unroll
    for(int rf = 0; rf < 2; ++rf){
      #pragma unroll
      for(int q = 0; q < 4; ++q){
        int rloc = rf*16 + rq*4 + q;
        float y = fmaxf(ax1[j][rf][q] + bv, 0.f);
        s_bh[rloc*BSTR + col] = f2bf(y);
      }
    }
  }
  __syncthreads();
  // ---- phase 5: x2 = relu(x1 @ W2 + b2); wave w -> col-frag w (NT=8) ----
  f32x4 ax2[2];
  #pragma unroll
  for(int rf = 0; rf < 2; ++rf) ax2[rf] = (f32x4){0.f,0.f,0.f,0.f};
  for(int kt = 0; kt < 8; ++kt){
    bf16x8 xh[2];
    #pragma unroll
    for(int rf = 0; rf < 2; ++rf){
      int off = (rf*16 + (l & 15))*BSTR + kt*32 + (l >> 4)*8;
      xh[rf] = *(const bf16x8*)(s_bh + off);
    }
    size_t bo = ((size_t)(kt*8 + w)*64 + l)*8;
    bf16x8 bh = *(const bf16x8*)(f2h + bo);
    bf16x8 bl = *(const bf16x8*)(f2l + bo);
    #pragma unroll
    for(int rf = 0; rf < 2; ++rf){
      ax2[rf] = __builtin_amdgcn_mfma_f32_16x16x32_bf16(xh[rf], bh, ax2[rf], 0, 0, 0);
      ax2[rf] = __builtin_amdgcn_mfma_f32_16x16x32_bf16(xh[rf], bl, ax2[rf], 0, 0, 0);
    }
  }
  {
    int col = w*16 + cl;
    float bv = b2[col];
    #pragma unroll
    for(int rf = 0; rf < 2; ++rf)
      #pragma unroll
      for(int q = 0; q < 4; ++q){
        int rloc = rf*16 + rq*4 + q;
        s_x2[rloc*XSTR + col] = fmaxf(ax2[rf][q] + bv, 0.f);
      }
  }
  __syncthreads();
  // ---- phase 6: W3 head + project_power; thread (rl = t>>4, j = t&15) ----
  {
    int j = t & 15, rl = t >> 4;   // 32 rows
    const float* xr = s_x2 + rl*XSTR;
    float raw = b3[j];
    #pragma unroll 8
    for(int k4 = 0; k4 < 32; ++k4){
      float4 v = *(const float4*)(xr + k4*4);
      raw += v.x*sW3[(k4*4+0)*16 + j] + v.y*sW3[(k4*4+1)*16 + j]
           + v.z*sW3[(k4*4+2)*16 + j] + v.w*sW3[(k4*4+3)*16 + j];
    }
    float c0 = fminf(fmaxf(raw, 0.f), 0.5f);
    float tot = c0;
    for(int off = 8; off; off >>= 1) tot += __shfl_xor(tot, off);
    float mx = raw;
    for(int off = 8; off; off >>= 1) mx = fmaxf(mx, __shfl_xor(mx, off));
    bool feas = (tot <= 1.0f);
    float lo = 0.f, hi = fmaxf(mx, 0.f);
    for(int it = 0; it < 60; ++it){
      float mid = 0.5f*(lo + hi);
      float s = fminf(fmaxf(raw - mid, 0.f), 0.5f);
      for(int off = 8; off; off >>= 1) s += __shfl_xor(s, off);
      bool over = s > 1.0f;
      lo = over ? mid : lo;
      hi = over ? hi : mid;
    }
    float muv = feas ? 0.f : hi;
    act[(size_t)(m0 + rl)*16 + j] = fminf(fmaxf(raw - muv, 0.f), 0.5f);
  }
}

// ---------- workspace layout (bytes) ----------
#define OFF_FLAG   0u
#define OFF_WAS    4096u
#define OFF_WAD    8192u
#define OFF_FFH    12288u        // 336 frags * 1024
#define OFF_FFL    356352u
#define OFF_WRZH   700416u       // 512 frags * 1024
#define OFF_WRZL   1224704u
#define OFF_WINH   1748992u      // 128 frags * 1024
#define OFF_WINL   1880064u
#define OFF_WHNH   2011136u
#define OFF_WHNL   2142208u
#define OFF_F1H    2273280u
#define OFF_F1L    2404352u
#define OFF_F2H    2535424u      // 64 frags * 1024
#define OFF_F2L    2600960u
#define OFF_XCATH  2666496u      // 8192*672*2 = 11010048
#define OFF_ACATH  13676544u     // 8192*512*2 = 8388608
// total: 22,065,152 bytes

extern "C" void kernel_launch(void* const* d_in, const int* in_sizes, int n_in,
                              void* d_out, int out_size, void* d_ws, size_t ws_size,
                              hipStream_t stream){
  const float* node   = (const float*)d_in[0];
  const float* nbr    = (const float*)d_in[1];
  const void*  mask   = d_in[2];
  const float* hidden = (const float*)d_in[3];
  const float* Wg     = (const float*)d_in[4];
  const float* ag     = (const float*)d_in[5];
  const float* fW     = (const float*)d_in[6];
  const float* fb     = (const float*)d_in[7];
  const float* Wih    = (const float*)d_in[8];
  const float* bih    = (const float*)d_in[9];
  const float* Whh    = (const float*)d_in[10];
  const float* bhh    = (const float*)d_in[11];
  const float* lng    = (const float*)d_in[12];
  const float* lnb    = (const float*)d_in[13];
  const float* W1     = (const float*)d_in[14];
  const float* b1     = (const float*)d_in[15];
  const float* W2     = (const float*)d_in[16];
  const float* b2     = (const float*)d_in[17];
  const float* W3     = (const float*)d_in[18];
  const float* b3     = (const float*)d_in[19];
  char* ws = (char*)d_ws;
  float* out = (float*)d_out;

  int*   flag = (int*)  (ws + OFF_FLAG);
  float* was  = (float*)(ws + OFF_WAS);
  float* wad  = (float*)(ws + OFF_WAD);
  u16* ffh  = (u16*)(ws + OFF_FFH);   u16* ffl  = (u16*)(ws + OFF_FFL);
  u16* wrzh = (u16*)(ws + OFF_WRZH);  u16* wrzl = (u16*)(ws + OFF_WRZL);
  u16* winh = (u16*)(ws + OFF_WINH);  u16* winl = (u16*)(ws + OFF_WINL);
  u16* whnh = (u16*)(ws + OFF_WHNH);  u16* whnl = (u16*)(ws + OFF_WHNL);
  u16* f1h  = (u16*)(ws + OFF_F1H);   u16* f1l  = (u16*)(ws + OFF_F1L);
  u16* f2h  = (u16*)(ws + OFF_F2H);   u16* f2l  = (u16*)(ws + OFF_F2L);
  u16* xh   = (u16*)(ws + OFF_XCATH);
  u16* ach  = (u16*)(ws + OFF_ACATH);

  // prep: single launch (incl. wbig frags)
  k_prep<<<325, 256, 0, stream>>>((const unsigned char*)mask, flag, Wg, ag, was, wad,
                                  fW, Wih, Whh, W1, W2,
                                  ffh, ffl, wrzh, wrzl, winh, winl, whnh, whnl,
                                  f1h, f1l, f2h, f2l);

  // GAT main (8192) + h-split tail (1024); single-plane outputs
  k_gat<<<8192 + 1024, 256, 0, stream>>>(nbr, node, mask, flag, was, wad, xh,
                                         hidden, ach);

  // fused = relu(x_cat @ Wbig + fb) -> ACAT cols 0..255; 512 blocks (2/CU)
  k_gemmF<21,16,2,2><<<dim3(256,2), 256, 0, stream>>>(xh, KFUSE, ffh, ffl, fb, ach, 512, 0);

  // GRU + LN + MLP + head + project, all fused (all activations single-plane)
  k_grumlp<<<256, 512, 0, stream>>>(ach, wrzh, wrzl, winh, winl, whnh, whnl,
                                    f1h, f1l, f2h, f2l, bih, bhh, hidden, lng, lnb,
                                    b1, b2, W3, b3, out + ACT_TOT, out);
}

// Round 18
// 165.532 us; speedup vs baseline: 1.0577x; 1.0577x over previous
//
#include <hip/hip_runtime.h>
#include <hip/hip_bf16.h>

// ActorNetwork fused pipeline for MI355X — round 18 = round 16 verbatim (best: 166.1 us).
// x_cat/ACAT single-plane bf16 activations; all weights hi/lo split bf16 (fp32-accurate).
// 4 kernels: prep(325) -> gat(9216) -> fusionGEMM(512x2) -> grumlp(256x512thr).

typedef unsigned short u16;
typedef unsigned int   u32;
typedef __attribute__((ext_vector_type(8))) short bf16x8;
typedef __attribute__((ext_vector_type(4))) float f32x4;

#define KFUSE  672   // 641 padded to 21*32
#define ACT_TOT (8192*16)

__device__ __forceinline__ u16 f2bf(float x){
  u32 u = __float_as_uint(x);
  u += 0x7fffu + ((u >> 16) & 1u);   // round-to-nearest-even
  return (u16)(u >> 16);
}
__device__ __forceinline__ float bf2f(u16 h){ return __uint_as_float(((u32)h) << 16); }

// one MFMA B-fragment (64 lanes) from fp32 src
__device__ __forceinline__ void frag_one(const float* __restrict__ src, int ld, int col0,
                                         int NT, u16* __restrict__ dhi, u16* __restrict__ dlo,
                                         int f, int fsrc, int l){
  int kt = fsrc / NT, nt = fsrc % NT;
  int kbase = kt*32 + (l >> 4)*8, n = col0 + nt*16 + (l & 15);
  size_t o = ((size_t)f*64 + l)*8;
  #pragma unroll
  for(int i = 0; i < 8; ++i){
    float w = src[(size_t)(kbase + i)*ld + n];
    u16 h = f2bf(w);
    dhi[o + i] = h;
    dlo[o + i] = f2bf(w - bf2f(h));
  }
}

// Wbig fragment computed inline: row r<129 -> fusion_W; 129..640 -> Wg x fW; pad 0
__device__ __forceinline__ void frag_wbig(const float* __restrict__ fW,
                                          const float* __restrict__ Wg,
                                          u16* __restrict__ dhi, u16* __restrict__ dlo,
                                          int f, int l){
  int kt = f / 16, nt = f % 16;
  int kbase = kt*32 + (l >> 4)*8, n = nt*16 + (l & 15);
  size_t o = ((size_t)f*64 + l)*8;
  #pragma unroll
  for(int i = 0; i < 8; ++i){
    int r = kbase + i;
    float v;
    if(r < 129) v = fW[(size_t)r*256 + n];
    else if(r < 641){
      int h = (r - 129) >> 7, kk = (r - 129) & 127;
      float s = 0.f;
      for(int ff = 0; ff < 64; ++ff)
        s += Wg[kk*256 + h*64 + ff] * fW[(size_t)(129 + h*64 + ff)*256 + n];
      v = s;
    } else v = 0.f;
    u16 hh = f2bf(v);
    dhi[o + i] = hh;
    dlo[o + i] = f2bf(v - bf2f(hh));
  }
}

// ---------- single prep kernel: probe+wa + all weight frags ----------
#define P_FF0   1
#define P_WRZ0  85
#define P_WIN0  213
#define P_WHN0  245
#define P_F10   277
#define P_F20   309
// grid = 325
__global__ __launch_bounds__(256) void k_prep(
    const unsigned char* __restrict__ maskb, int* __restrict__ flag,
    const float* __restrict__ Wg, const float* __restrict__ ag,
    float* __restrict__ was, float* __restrict__ wad,
    const float* __restrict__ fW,
    const float* __restrict__ Wih, const float* __restrict__ Whh,
    const float* __restrict__ W1, const float* __restrict__ W2,
    u16* __restrict__ ffh, u16* __restrict__ ffl,
    u16* __restrict__ wrzh, u16* __restrict__ wrzl,
    u16* __restrict__ winh, u16* __restrict__ winl,
    u16* __restrict__ whnh, u16* __restrict__ whnl,
    u16* __restrict__ f1h, u16* __restrict__ f1l,
    u16* __restrict__ f2h, u16* __restrict__ f2l)
{
  int bx = blockIdx.x, t = threadIdx.x;
  if(bx == 0){
    if(t == 0){
      int s = 0;
      for(int i = 1; i < 256; i += 4) s += maskb[i];
      *flag = (s == 0) ? 1 : 0;
    }
    #pragma unroll
    for(int v = 0; v < 2; ++v){
      int idx = v*256 + t, k = idx & 127, h = idx >> 7;
      float s = 0.f, d = 0.f;
      for(int f = 0; f < 64; ++f){
        float w = Wg[k*256 + h*64 + f];
        s += w * ag[h*128 + f];
        d += w * ag[h*128 + 64 + f];
      }
      was[k*4 + h] = s; wad[k*4 + h] = d;
    }
  } else if(bx < P_WRZ0){
    int sub = t >> 6, l = t & 63;
    int f = (bx - P_FF0)*4 + sub;          // 0..335
    frag_wbig(fW, Wg, ffh, ffl, f, l);
  } else {
    int sub = t >> 6, l = t & 63;
    if(bx < P_WIN0){        // rz: 512 frags (Wih 0..255, Whh 256..511)
      int idx = (bx - P_WRZ0)*4 + sub;
      if(idx < 256) frag_one(Wih, 768, 0, 32, wrzh, wrzl, idx, idx, l);
      else          frag_one(Whh, 768, 0, 32, wrzh, wrzl, idx, idx - 256, l);
    } else if(bx < P_WHN0){ // Wih n
      int f = (bx - P_WIN0)*4 + sub;
      frag_one(Wih, 768, 512, 16, winh, winl, f, f, l);
    } else if(bx < P_F10){  // Whh n
      int f = (bx - P_WHN0)*4 + sub;
      frag_one(Whh, 768, 512, 16, whnh, whnl, f, f, l);
    } else if(bx < P_F20){  // W1
      int f = (bx - P_F10)*4 + sub;
      frag_one(W1, 256, 0, 16, f1h, f1l, f, f, l);
    } else {                // W2
      int f = (bx - P_F20)*4 + sub;
      frag_one(W2, 128, 0, 8, f2h, f2l, f, f, l);
    }
  }
}

// ---------- GAT kernel: main 8192 + h-split tail 1024; single-plane outputs ----------
__global__ __launch_bounds__(256) void k_gat(
    const float* __restrict__ nbg, const float* __restrict__ node,
    const void* __restrict__ maskp, const int* __restrict__ flagp,
    const float* __restrict__ was, const float* __restrict__ wad,
    u16* __restrict__ xhi,
    const float* __restrict__ hidden,
    u16* __restrict__ acath)
{
  int t = threadIdx.x;
  if(blockIdx.x >= 8192){
    int i = (blockIdx.x - 8192)*256 + t;
    int idx8 = i*8, row = idx8 >> 8, col = idx8 & 255;
    const float4* p = (const float4*)(hidden + (size_t)idx8);
    float4 v0 = p[0], v1 = p[1];
    float vv[8] = {v0.x,v0.y,v0.z,v0.w,v1.x,v1.y,v1.z,v1.w};
    u16 h8[8];
    #pragma unroll
    for(int q = 0; q < 8; ++q) h8[q] = f2bf(vv[q]);
    uint4 uh = { (u32)h8[0] | ((u32)h8[1]<<16), (u32)h8[2] | ((u32)h8[3]<<16),
                 (u32)h8[4] | ((u32)h8[5]<<16), (u32)h8[6] | ((u32)h8[7]<<16) };
    size_t off = (size_t)row*512 + 256 + col;
    *(uint4*)(acath + off) = uh;
    return;
  }

  __shared__ float s_nb[8192];
  __shared__ float s_ep[1024];
  __shared__ float s_alpha[256];
  int b = blockIdx.x;
  const float* nb = nbg + (size_t)b*8192;
  const int isint = *flagp;

  #pragma unroll
  for(int q = 0; q < 8; ++q){
    int f = q*256 + t;
    int n = f >> 5, ch = f & 31;
    float4 v = *(const float4*)(nb + f*4);
    *(float4*)(s_nb + (n*32 + (ch ^ (n & 31)))*4) = v;
  }

  if(t < 129){
    float v;
    if(t < 2){
      float ph = node[(size_t)b*128] * (6.2831853071795864769f / 24.0f);
      v = (t == 0) ? sinf(ph) : cosf(ph);
    } else v = node[(size_t)b*128 + (t-1)];
    xhi[(size_t)b*KFUSE + t] = f2bf(v);
  } else if(t < 160){
    xhi[(size_t)b*KFUSE + 641 + (t - 129)] = 0;
  }
  __syncthreads();

  {
    int n = t & 63, c = t >> 6;
    int cu = __builtin_amdgcn_readfirstlane(c);
    const float* wadc = wad + cu*128;
    float adx = 0.f, ady = 0.f, adz = 0.f, adw = 0.f;
    #pragma unroll
    for(int q = 0; q < 8; ++q){
      int ch = c*8 + q;
      float4 v = *(const float4*)(s_nb + (n*32 + (ch ^ (n & 31)))*4);
      float vv[4] = {v.x, v.y, v.z, v.w};
      #pragma unroll
      for(int i2 = 0; i2 < 4; ++i2){
        float4 wd = *(const float4*)(wadc + (q*4 + i2)*4);
        adx += vv[i2]*wd.x; ady += vv[i2]*wd.y; adz += vv[i2]*wd.z; adw += vv[i2]*wd.w;
      }
    }
    float4 ad = {adx, ady, adz, adw};
    *(float4*)(s_ep + (c*64 + n)*4) = ad;
  }
  __syncthreads();

  {
    int n2 = t & 63, h2 = t >> 6;
    float es = 0.f;
    #pragma unroll
    for(int ii = 0; ii < 2; ++ii){
      int k = n2*2 + ii;
      float v0 = s_nb[(k >> 2)*4 + (k & 3)];
      es += v0 * was[k*4 + h2];
    }
    for(int off = 32; off; off >>= 1) es += __shfl_xor(es, off);
    float ed = s_ep[n2*4 + h2] + s_ep[(64+n2)*4 + h2]
             + s_ep[(128+n2)*4 + h2] + s_ep[(192+n2)*4 + h2];
    float e = es + ed;
    e = (e > 0.f) ? e : 0.2f*e;
    bool valid;
    if(isint) valid = ((const u32*)maskp)[(size_t)b*64 + n2] != 0u;
    else      valid = ((const unsigned char*)maskp)[(size_t)b*64 + n2] != 0;
    float ev = valid ? e : -1e30f;
    float m = ev;
    for(int off = 32; off; off >>= 1) m = fmaxf(m, __shfl_xor(m, off));
    float p = valid ? expf(ev - m) : 0.f;
    float s = p;
    for(int off = 32; off; off >>= 1) s += __shfl_xor(s, off);
    s_alpha[n2*4 + h2] = p / s;   // [n][4h]
  }
  __syncthreads();

  {
    int c2 = t & 31, hp = (t >> 6) & 1, half = t >> 7;
    int sub = (t >> 5) & 1;
    float4 a0 = {0.f,0.f,0.f,0.f}, a1 = {0.f,0.f,0.f,0.f};
    int nbase = half*32 + sub*16;
    #pragma unroll
    for(int i = 0; i < 16; ++i){
      int n = nbase + i;
      float4 v = *(const float4*)(s_nb + (n*32 + (c2 ^ (n & 31)))*4);
      float2 ap = *(const float2*)(s_alpha + n*4 + hp*2);
      a0.x += ap.x*v.x; a0.y += ap.x*v.y; a0.z += ap.x*v.z; a0.w += ap.x*v.w;
      a1.x += ap.y*v.x; a1.y += ap.y*v.y; a1.z += ap.y*v.z; a1.w += ap.y*v.w;
    }
    a0.x += __shfl_xor(a0.x, 32); a0.y += __shfl_xor(a0.y, 32);
    a0.z += __shfl_xor(a0.z, 32); a0.w += __shfl_xor(a0.w, 32);
    a1.x += __shfl_xor(a1.x, 32); a1.y += __shfl_xor(a1.y, 32);
    a1.z += __shfl_xor(a1.z, 32); a1.w += __shfl_xor(a1.w, 32);
    __syncthreads();
    if((t & 63) < 32){
      int w = t >> 6;
      *(float4*)(s_ep + (w*32 + c2)*8 + 0) = a0;
      *(float4*)(s_ep + (w*32 + c2)*8 + 4) = a1;
    }
  }
  __syncthreads();
  if(t < 128){
    int h = t >> 5, cc = t & 31;
    int hp2 = h >> 1, slot = h & 1;
    float4 p0 = *(const float4*)(s_ep + ((0*2 + hp2)*32 + cc)*8 + slot*4);
    float4 p1 = *(const float4*)(s_ep + ((1*2 + hp2)*32 + cc)*8 + slot*4);
    float vv[4] = {p0.x+p1.x, p0.y+p1.y, p0.z+p1.z, p0.w+p1.w};
    size_t o = (size_t)b*KFUSE + 129 + h*128 + cc*4;
    #pragma unroll
    for(int i = 0; i < 4; ++i) xhi[o+i] = f2bf(vv[i]);
  }
}

// ---------- fusion GEMM: A single-plane, B hi/lo split; single-plane output ----------
template<int KT, int NT_TOT, int NPW, int ROWF>
__global__ __launch_bounds__(256) void k_gemmF(
    const u16* __restrict__ xhi, int lda,
    const u16* __restrict__ wfhi, const u16* __restrict__ wflo,
    const float* __restrict__ bias,
    u16* __restrict__ ohi, int ost, int ocol)
{
  int l = threadIdx.x & 63, w = threadIdx.x >> 6;
  int m0 = blockIdx.x * (16*ROWF);
  int ntbase = blockIdx.y * (4*NPW) + w*NPW;
  f32x4 acc[NPW][ROWF];
  #pragma unroll
  for(int j = 0; j < NPW; ++j)
    #pragma unroll
    for(int rf = 0; rf < ROWF; ++rf) acc[j][rf] = (f32x4){0.f,0.f,0.f,0.f};
  size_t arow[ROWF];
  #pragma unroll
  for(int rf = 0; rf < ROWF; ++rf)
    arow[rf] = (size_t)(m0 + rf*16 + (l & 15))*lda + (size_t)((l >> 4)*8);
  bf16x8 ah[ROWF], bhc[NPW], blc[NPW];
  #pragma unroll
  for(int rf = 0; rf < ROWF; ++rf)
    ah[rf] = *(const bf16x8*)(xhi + arow[rf]);
  #pragma unroll
  for(int j = 0; j < NPW; ++j){
    size_t bo = ((size_t)(ntbase + j)*64 + l)*8;
    bhc[j] = *(const bf16x8*)(wfhi + bo);
    blc[j] = *(const bf16x8*)(wflo + bo);
  }
  for(int kt = 0; kt < KT; ++kt){
    bf16x8 ahn[ROWF], bhn[NPW], bln[NPW];
    if(kt + 1 < KT){
      #pragma unroll
      for(int rf = 0; rf < ROWF; ++rf)
        ahn[rf] = *(const bf16x8*)(xhi + arow[rf] + (kt+1)*32);
      #pragma unroll
      for(int j = 0; j < NPW; ++j){
        size_t bo = ((size_t)((kt+1)*NT_TOT + ntbase + j)*64 + l)*8;
        bhn[j] = *(const bf16x8*)(wfhi + bo);
        bln[j] = *(const bf16x8*)(wflo + bo);
      }
    }
    #pragma unroll
    for(int j = 0; j < NPW; ++j){
      #pragma unroll
      for(int rf = 0; rf < ROWF; ++rf){
        acc[j][rf] = __builtin_amdgcn_mfma_f32_16x16x32_bf16(ah[rf], bhc[j], acc[j][rf], 0, 0, 0);
        acc[j][rf] = __builtin_amdgcn_mfma_f32_16x16x32_bf16(ah[rf], blc[j], acc[j][rf], 0, 0, 0);
      }
    }
    #pragma unroll
    for(int rf = 0; rf < ROWF; ++rf) ah[rf] = ahn[rf];
    #pragma unroll
    for(int j = 0; j < NPW; ++j){ bhc[j] = bhn[j]; blc[j] = bln[j]; }
  }
  #pragma unroll
  for(int j = 0; j < NPW; ++j){
    int col = (ntbase + j)*16 + (l & 15);
    float bv = bias[col];
    #pragma unroll
    for(int rf = 0; rf < ROWF; ++rf){
      int r0 = m0 + rf*16 + (l >> 4)*4;
      #pragma unroll
      for(int q = 0; q < 4; ++q){
        float y = fmaxf(acc[j][rf][q] + bv, 0.f);
        ohi[(size_t)(r0 + q)*ost + ocol + col] = f2bf(y);
      }
    }
  }
}

// ---------- mega kernel: GRU(A single-plane) + LN + W1 + W2 + head + project ----------
#define BSTR 264   // padded u16 stride for bel/x1 tile
#define XSTR 132   // padded f32 stride for x2 tile
__global__ __launch_bounds__(512) void k_grumlp(
    const u16* __restrict__ ah_,
    const u16* __restrict__ wrzh, const u16* __restrict__ wrzl,
    const u16* __restrict__ winh, const u16* __restrict__ winl,
    const u16* __restrict__ whnh, const u16* __restrict__ whnl,
    const u16* __restrict__ f1h, const u16* __restrict__ f1l,
    const u16* __restrict__ f2h, const u16* __restrict__ f2l,
    const float* __restrict__ bih, const float* __restrict__ bhh,
    const float* __restrict__ hidden, const float* __restrict__ lng,
    const float* __restrict__ lnb,
    const float* __restrict__ b1, const float* __restrict__ b2,
    const float* __restrict__ W3, const float* __restrict__ b3,
    float* __restrict__ hout, float* __restrict__ act)
{
  __shared__ float s_s1[256], s_s2[256], s_mu[32], s_rs[32];
  __shared__ u16 s_bh[32*BSTR], s_bl[32*BSTR];   // bel tile, later x1 tile
  __shared__ float s_x2[32*XSTR];
  __shared__ float sW3[2048];
  int t = threadIdx.x;
  int l = t & 63, w = t >> 6;   // 8 waves
  int m0 = blockIdx.x*32;
  for(int i = t; i < 2048; i += 512) sW3[i] = W3[i];

  // ---- phase 1: GRU gates via MFMA (A single-plane, weights split) ----
  f32x4 ar[2][2], az[2][2], aa[2][2], ab[2][2];
  #pragma unroll
  for(int j = 0; j < 2; ++j)
    #pragma unroll
    for(int rf = 0; rf < 2; ++rf){
      ar[j][rf] = (f32x4){0.f,0.f,0.f,0.f}; az[j][rf] = (f32x4){0.f,0.f,0.f,0.f};
      aa[j][rf] = (f32x4){0.f,0.f,0.f,0.f}; ab[j][rf] = (f32x4){0.f,0.f,0.f,0.f};
    }
  size_t arow[2];
  #pragma unroll
  for(int rf = 0; rf < 2; ++rf)
    arow[rf] = (size_t)(m0 + rf*16 + (l & 15))*512 + (size_t)((l >> 4)*8);
  for(int kt = 0; kt < 16; ++kt){
    bf16x8 xh[2];
    #pragma unroll
    for(int rf = 0; rf < 2; ++rf)
      xh[rf] = *(const bf16x8*)(ah_ + arow[rf] + kt*32);
    #pragma unroll
    for(int j = 0; j < 2; ++j){
      int nt = w*2 + j;
      size_t bo = ((size_t)(kt*32 + nt)*64 + l)*8;
      bf16x8 bh = *(const bf16x8*)(wrzh + bo);
      bf16x8 bl = *(const bf16x8*)(wrzl + bo);
      size_t bo2 = bo + (size_t)16*64*8;
      bf16x8 bh2 = *(const bf16x8*)(wrzh + bo2);
      bf16x8 bl2 = *(const bf16x8*)(wrzl + bo2);
      #pragma unroll
      for(int rf = 0; rf < 2; ++rf){
        ar[j][rf] = __builtin_amdgcn_mfma_f32_16x16x32_bf16(xh[rf], bh, ar[j][rf], 0, 0, 0);
        ar[j][rf] = __builtin_amdgcn_mfma_f32_16x16x32_bf16(xh[rf], bl, ar[j][rf], 0, 0, 0);
        az[j][rf] = __builtin_amdgcn_mfma_f32_16x16x32_bf16(xh[rf], bh2, az[j][rf], 0, 0, 0);
        az[j][rf] = __builtin_amdgcn_mfma_f32_16x16x32_bf16(xh[rf], bl2, az[j][rf], 0, 0, 0);
      }
    }
  }
  for(int kt = 0; kt < 8; ++kt){
    bf16x8 fh[2], gh[2];
    #pragma unroll
    for(int rf = 0; rf < 2; ++rf){
      fh[rf] = *(const bf16x8*)(ah_ + arow[rf] + kt*32);
      gh[rf] = *(const bf16x8*)(ah_ + arow[rf] + 256 + kt*32);
    }
    #pragma unroll
    for(int j = 0; j < 2; ++j){
      int nt = w*2 + j;
      size_t bo = ((size_t)(kt*16 + nt)*64 + l)*8;
      bf16x8 bh = *(const bf16x8*)(winh + bo);
      bf16x8 bl = *(const bf16x8*)(winl + bo);
      bf16x8 ch = *(const bf16x8*)(whnh + bo);
      bf16x8 cl2 = *(const bf16x8*)(whnl + bo);
      #pragma unroll
      for(int rf = 0; rf < 2; ++rf){
        aa[j][rf] = __builtin_amdgcn_mfma_f32_16x16x32_bf16(fh[rf], bh, aa[j][rf], 0, 0, 0);
        aa[j][rf] = __builtin_amdgcn_mfma_f32_16x16x32_bf16(fh[rf], bl, aa[j][rf], 0, 0, 0);
        ab[j][rf] = __builtin_amdgcn_mfma_f32_16x16x32_bf16(gh[rf], ch, ab[j][rf], 0, 0, 0);
        ab[j][rf] = __builtin_amdgcn_mfma_f32_16x16x32_bf16(gh[rf], cl2, ab[j][rf], 0, 0, 0);
      }
    }
  }
  int cl = l & 15, rq = l >> 4;
  float hnew[2][2][4];
  float s1p[2][4], s2p[2][4];
  #pragma unroll
  for(int rf = 0; rf < 2; ++rf)
    #pragma unroll
    for(int q = 0; q < 4; ++q){ s1p[rf][q] = 0.f; s2p[rf][q] = 0.f; }
  #pragma unroll
  for(int j = 0; j < 2; ++j){
    int col = w*32 + j*16 + cl;
    float br = bih[col] + bhh[col];
    float bz = bih[256+col] + bhh[256+col];
    float bi = bih[512+col];
    float bh2 = bhh[512+col];
    #pragma unroll
    for(int rf = 0; rf < 2; ++rf){
      #pragma unroll
      for(int q = 0; q < 4; ++q){
        int row = m0 + rf*16 + rq*4 + q;
        float rs = ar[j][rf][q] + br;
        float zs = az[j][rf][q] + bz;
        float in_ = aa[j][rf][q] + bi;
        float hn  = ab[j][rf][q] + bh2;
        float h   = hidden[(size_t)row*256 + col];
        float r = 1.f/(1.f + expf(-rs));
        float z = 1.f/(1.f + expf(-zs));
        float nv = tanhf(in_ + r*hn);
        float hv = (1.f - z)*nv + z*h;
        hnew[j][rf][q] = hv;
        hout[(size_t)row*256 + col] = hv;
        s1p[rf][q] += hv; s2p[rf][q] += hv*hv;
      }
    }
  }
  #pragma unroll
  for(int rf = 0; rf < 2; ++rf)
    #pragma unroll
    for(int q = 0; q < 4; ++q){
      float a = s1p[rf][q], b2v = s2p[rf][q];
      for(int off = 1; off < 16; off <<= 1){
        a += __shfl_xor(a, off); b2v += __shfl_xor(b2v, off);
      }
      if(cl == 0){
        int rloc = rf*16 + rq*4 + q;
        s_s1[w*32 + rloc] = a; s_s2[w*32 + rloc] = b2v;
      }
    }
  __syncthreads();
  if(t < 32){
    int rloc = t;
    float t1 = 0.f, t2 = 0.f;
    #pragma unroll
    for(int ww = 0; ww < 8; ++ww){ t1 += s_s1[ww*32 + rloc]; t2 += s_s2[ww*32 + rloc]; }
    float mu = t1 * (1.f/256.f);
    float var = t2 * (1.f/256.f) - mu*mu;
    s_mu[rloc] = mu; s_rs[rloc] = rsqrtf(var + 1e-5f);
  }
  __syncthreads();
  // ---- phase 2: bel -> LDS tile (hi/lo) ----
  #pragma unroll
  for(int j = 0; j < 2; ++j){
    int col = w*32 + j*16 + cl;
    float g = lng[col], bb = lnb[col];
    #pragma unroll
    for(int rf = 0; rf < 2; ++rf){
      #pragma unroll
      for(int q = 0; q < 4; ++q){
        int rloc = rf*16 + rq*4 + q;
        float bel = (hnew[j][rf][q] - s_mu[rloc]) * s_rs[rloc] * g + bb;
        u16 hb = f2bf(bel);
        s_bh[rloc*BSTR + col] = hb;
        s_bl[rloc*BSTR + col] = f2bf(bel - bf2f(hb));
      }
    }
  }
  __syncthreads();
  // ---- phase 3: x1 = relu(bel @ W1 + b1), bel from LDS ----
  f32x4 ax1[2][2];
  #pragma unroll
  for(int j = 0; j < 2; ++j)
    #pragma unroll
    for(int rf = 0; rf < 2; ++rf) ax1[j][rf] = (f32x4){0.f,0.f,0.f,0.f};
  for(int kt = 0; kt < 8; ++kt){
    bf16x8 xh[2], xl[2];
    #pragma unroll
    for(int rf = 0; rf < 2; ++rf){
      int off = (rf*16 + (l & 15))*BSTR + kt*32 + (l >> 4)*8;
      xh[rf] = *(const bf16x8*)(s_bh + off);
      xl[rf] = *(const bf16x8*)(s_bl + off);
    }
    #pragma unroll
    for(int j = 0; j < 2; ++j){
      size_t bo = ((size_t)(kt*16 + w*2 + j)*64 + l)*8;
      bf16x8 bh = *(const bf16x8*)(f1h + bo);
      bf16x8 bl = *(const bf16x8*)(f1l + bo);
      #pragma unroll
      for(int rf = 0; rf < 2; ++rf){
        ax1[j][rf] = __builtin_amdgcn_mfma_f32_16x16x32_bf16(xh[rf], bh, ax1[j][rf], 0, 0, 0);
        ax1[j][rf] = __builtin_amdgcn_mfma_f32_16x16x32_bf16(xh[rf], bl, ax1[j][rf], 0, 0, 0);
        ax1[j][rf] = __builtin_amdgcn_mfma_f32_16x16x32_bf16(xl[rf], bh, ax1[j][rf], 0, 0, 0);
      }
    }
  }
  __syncthreads();
  // ---- phase 4: x1 -> LDS tile (overwrite bel) ----
  #pragma unroll
  for(int j = 0; j < 2; ++j){
    int col = (w*2 + j)*16 + cl;
    float bv = b1[col];
    #pragma unroll
    for(int rf = 0; rf < 2; ++rf){
      #pragma unroll
      for(int q = 0; q < 4; ++q){
        int rloc = rf*16 + rq*4 + q;
        float y = fmaxf(ax1[j][rf][q] + bv, 0.f);
        u16 hh = f2bf(y);
        s_bh[rloc*BSTR + col] = hh;
        s_bl[rloc*BSTR + col] = f2bf(y - bf2f(hh));
      }
    }
  }
  __syncthreads();
  // ---- phase 5: x2 = relu(x1 @ W2 + b2); wave w -> col-frag w (NT=8) ----
  f32x4 ax2[2];
  #pragma unroll
  for(int rf = 0; rf < 2; ++rf) ax2[rf] = (f32x4){0.f,0.f,0.f,0.f};
  for(int kt = 0; kt < 8; ++kt){
    bf16x8 xh[2], xl[2];
    #pragma unroll
    for(int rf = 0; rf < 2; ++rf){
      int off = (rf*16 + (l & 15))*BSTR + kt*32 + (l >> 4)*8;
      xh[rf] = *(const bf16x8*)(s_bh + off);
      xl[rf] = *(const bf16x8*)(s_bl + off);
    }
    size_t bo = ((size_t)(kt*8 + w)*64 + l)*8;
    bf16x8 bh = *(const bf16x8*)(f2h + bo);
    bf16x8 bl = *(const bf16x8*)(f2l + bo);
    #pragma unroll
    for(int rf = 0; rf < 2; ++rf){
      ax2[rf] = __builtin_amdgcn_mfma_f32_16x16x32_bf16(xh[rf], bh, ax2[rf], 0, 0, 0);
      ax2[rf] = __builtin_amdgcn_mfma_f32_16x16x32_bf16(xh[rf], bl, ax2[rf], 0, 0, 0);
      ax2[rf] = __builtin_amdgcn_mfma_f32_16x16x32_bf16(xl[rf], bh, ax2[rf], 0, 0, 0);
    }
  }
  {
    int col = w*16 + cl;
    float bv = b2[col];
    #pragma unroll
    for(int rf = 0; rf < 2; ++rf)
      #pragma unroll
      for(int q = 0; q < 4; ++q){
        int rloc = rf*16 + rq*4 + q;
        s_x2[rloc*XSTR + col] = fmaxf(ax2[rf][q] + bv, 0.f);
      }
  }
  __syncthreads();
  // ---- phase 6: W3 head + project_power; thread (rl = t>>4, j = t&15) ----
  {
    int j = t & 15, rl = t >> 4;   // 32 rows
    const float* xr = s_x2 + rl*XSTR;
    float raw = b3[j];
    #pragma unroll 8
    for(int k4 = 0; k4 < 32; ++k4){
      float4 v = *(const float4*)(xr + k4*4);
      raw += v.x*sW3[(k4*4+0)*16 + j] + v.y*sW3[(k4*4+1)*16 + j]
           + v.z*sW3[(k4*4+2)*16 + j] + v.w*sW3[(k4*4+3)*16 + j];
    }
    float c0 = fminf(fmaxf(raw, 0.f), 0.5f);
    float tot = c0;
    for(int off = 8; off; off >>= 1) tot += __shfl_xor(tot, off);
    float mx = raw;
    for(int off = 8; off; off >>= 1) mx = fmaxf(mx, __shfl_xor(mx, off));
    bool feas = (tot <= 1.0f);
    float lo = 0.f, hi = fmaxf(mx, 0.f);
    for(int it = 0; it < 60; ++it){
      float mid = 0.5f*(lo + hi);
      float s = fminf(fmaxf(raw - mid, 0.f), 0.5f);
      for(int off = 8; off; off >>= 1) s += __shfl_xor(s, off);
      bool over = s > 1.0f;
      lo = over ? mid : lo;
      hi = over ? hi : mid;
    }
    float muv = feas ? 0.f : hi;
    act[(size_t)(m0 + rl)*16 + j] = fminf(fmaxf(raw - muv, 0.f), 0.5f);
  }
}

// ---------- workspace layout (bytes) ----------
#define OFF_FLAG   0u
#define OFF_WAS    4096u
#define OFF_WAD    8192u
#define OFF_FFH    12288u        // 336 frags * 1024
#define OFF_FFL    356352u
#define OFF_WRZH   700416u       // 512 frags * 1024
#define OFF_WRZL   1224704u
#define OFF_WINH   1748992u      // 128 frags * 1024
#define OFF_WINL   1880064u
#define OFF_WHNH   2011136u
#define OFF_WHNL   2142208u
#define OFF_F1H    2273280u
#define OFF_F1L    2404352u
#define OFF_F2H    2535424u      // 64 frags * 1024
#define OFF_F2L    2600960u
#define OFF_XCATH  2666496u      // 8192*672*2 = 11010048
#define OFF_ACATH  13676544u     // 8192*512*2 = 8388608
// total: 22,065,152 bytes

extern "C" void kernel_launch(void* const* d_in, const int* in_sizes, int n_in,
                              void* d_out, int out_size, void* d_ws, size_t ws_size,
                              hipStream_t stream){
  const float* node   = (const float*)d_in[0];
  const float* nbr    = (const float*)d_in[1];
  const void*  mask   = d_in[2];
  const float* hidden = (const float*)d_in[3];
  const float* Wg     = (const float*)d_in[4];
  const float* ag     = (const float*)d_in[5];
  const float* fW     = (const float*)d_in[6];
  const float* fb     = (const float*)d_in[7];
  const float* Wih    = (const float*)d_in[8];
  const float* bih    = (const float*)d_in[9];
  const float* Whh    = (const float*)d_in[10];
  const float* bhh    = (const float*)d_in[11];
  const float* lng    = (const float*)d_in[12];
  const float* lnb    = (const float*)d_in[13];
  const float* W1     = (const float*)d_in[14];
  const float* b1     = (const float*)d_in[15];
  const float* W2     = (const float*)d_in[16];
  const float* b2     = (const float*)d_in[17];
  const float* W3     = (const float*)d_in[18];
  const float* b3     = (const float*)d_in[19];
  char* ws = (char*)d_ws;
  float* out = (float*)d_out;

  int*   flag = (int*)  (ws + OFF_FLAG);
  float* was  = (float*)(ws + OFF_WAS);
  float* wad  = (float*)(ws + OFF_WAD);
  u16* ffh  = (u16*)(ws + OFF_FFH);   u16* ffl  = (u16*)(ws + OFF_FFL);
  u16* wrzh = (u16*)(ws + OFF_WRZH);  u16* wrzl = (u16*)(ws + OFF_WRZL);
  u16* winh = (u16*)(ws + OFF_WINH);  u16* winl = (u16*)(ws + OFF_WINL);
  u16* whnh = (u16*)(ws + OFF_WHNH);  u16* whnl = (u16*)(ws + OFF_WHNL);
  u16* f1h  = (u16*)(ws + OFF_F1H);   u16* f1l  = (u16*)(ws + OFF_F1L);
  u16* f2h  = (u16*)(ws + OFF_F2H);   u16* f2l  = (u16*)(ws + OFF_F2L);
  u16* xh   = (u16*)(ws + OFF_XCATH);
  u16* ach  = (u16*)(ws + OFF_ACATH);

  // prep: single launch (incl. wbig frags)
  k_prep<<<325, 256, 0, stream>>>((const unsigned char*)mask, flag, Wg, ag, was, wad,
                                  fW, Wih, Whh, W1, W2,
                                  ffh, ffl, wrzh, wrzl, winh, winl, whnh, whnl,
                                  f1h, f1l, f2h, f2l);

  // GAT main (8192) + h-split tail (1024); single-plane outputs
  k_gat<<<8192 + 1024, 256, 0, stream>>>(nbr, node, mask, flag, was, wad, xh,
                                         hidden, ach);

  // fused = relu(x_cat @ Wbig + fb) -> ACAT cols 0..255; 512 blocks (2/CU)
  k_gemmF<21,16,2,2><<<dim3(256,2), 256, 0, stream>>>(xh, KFUSE, ffh, ffl, fb, ach, 512, 0);

  // GRU + LN + MLP + head + project, all fused (A single-plane)
  k_grumlp<<<256, 512, 0, stream>>>(ach, wrzh, wrzl, winh, winl, whnh, whnl,
                                    f1h, f1l, f2h, f2l, bih, bhh, hidden, lng, lnb,
                                    b1, b2, W3, b3, out + ACT_TOT, out);
}